// Round 9
// baseline (150.692 us; speedup 1.0000x reference)
//
#include <hip/hip_runtime.h>
#include <hip/hip_bf16.h>

// Fused MHA: B=2, T=2048, C=1024, H=16, dh=64.
// cvt_x -> qkv GEMM (A bf16 via global_load_lds, W fp32 reg-staged; V transposed via LDS
// in-epilogue, coalesced writes) -> flash attention (1024 blocks, XCD-local, defer-max)
// -> out GEMM (64x128 tiles). ws (32 MiB): Qb | Kb | VtG | Ob. d_out[0,8MB) = x_bf16 scratch.

typedef __attribute__((ext_vector_type(4))) float f32x4;
typedef __attribute__((ext_vector_type(4))) unsigned int u32x4;
typedef __attribute__((ext_vector_type(8))) __bf16 bf16x8;
typedef __attribute__((ext_vector_type(8))) unsigned short us8;
typedef __attribute__((ext_vector_type(4))) unsigned short us4;

#define LOG2E 1.4426950408889634f

__device__ __forceinline__ unsigned short f2bf(float f) {
    unsigned u = __builtin_bit_cast(unsigned, f);
    u += 0x7fffu + ((u >> 16) & 1u);   // round-to-nearest-even
    return (unsigned short)(u >> 16);
}

__device__ __forceinline__ unsigned cvt_pk_bf16(float lo, float hi) {
    unsigned r;
    asm("v_cvt_pk_bf16_f32 %0, %1, %2" : "=v"(r) : "v"(lo), "v"(hi));
    return r;
}

__device__ __forceinline__ f32x4 mfma16(us8 a, us8 b, f32x4 c) {
    return __builtin_amdgcn_mfma_f32_16x16x32_bf16(
        __builtin_bit_cast(bf16x8, a), __builtin_bit_cast(bf16x8, b), c, 0, 0, 0);
}

__device__ __forceinline__ void gload16(const unsigned short* gp, unsigned short* lp) {
    __builtin_amdgcn_global_load_lds(
        (const __attribute__((address_space(1))) void*)gp,
        (__attribute__((address_space(3))) void*)lp, 16, 0, 0);
}

__global__ __launch_bounds__(256) void fill_sentinel(float* __restrict__ out, int n) {
    int i = blockIdx.x * 256 + threadIdx.x;
    if (i < n) out[i] = 12345.0f;
}

__global__ __launch_bounds__(256) void cvt_x(const float* __restrict__ x,
                                             unsigned short* __restrict__ xb) {
    int idx = (blockIdx.x * 256 + threadIdx.x) * 4;
    f32x4 v = *(const f32x4*)(x + idx);
    us4 o = { f2bf(v[0]), f2bf(v[1]), f2bf(v[2]), f2bf(v[3]) };
    *(us4*)(xb + idx) = o;
}

// ---------------- mixed GEMM core: C[m][n] = sum_k A[m][k]*B[n][k] ----------------
// Tile (MI*32) x 128, BK=64, 256 threads = 4 waves (2x2); wave does (MI*16) x 64.
// A: bf16, staged via global_load_lds (linear LDS [MI*32][64]).
// B: fp32, reg-staged (loads issued BEFORE barrier-1 -> overlap prev tile's MFMA),
//    converted to bf16, stored to LDS padded 72 (2-way alias = free).
template <int MI>
__device__ __forceinline__ void gemm_core_m(
    const unsigned short* __restrict__ A, const float* __restrict__ Bf,
    int K, int m0, int n0, unsigned short* As, unsigned short* Bs, f32x4 acc[MI][4]) {
    const int tid = threadIdx.x;
    const int lane = tid & 63, wid = tid >> 6;
    const int g = lane >> 4, s = lane & 15;
    const int wr = wid >> 1, wc = wid & 1;
#pragma unroll
    for (int mi = 0; mi < MI; mi++)
#pragma unroll
        for (int ni = 0; ni < 4; ni++) acc[mi][ni] = (f32x4){0.f, 0.f, 0.f, 0.f};
    const int lrow = lane >> 3, lcol = (lane & 7) * 8;   // A gload lane pattern
    const int brow = tid >> 3, bcol = (tid & 7) * 8;     // B staging pattern
    for (int k0 = 0; k0 < K; k0 += 64) {
        // B global loads + cvt (pre-barrier: overlaps previous iteration's MFMA)
        us8 bv[4];
#pragma unroll
        for (int p = 0; p < 4; p++) {
            size_t boff = (size_t)(n0 + brow + p * 32) * K + k0 + bcol;
            f32x4 v0 = *(const f32x4*)(Bf + boff);
            f32x4 v1 = *(const f32x4*)(Bf + boff + 4);
            bv[p] = (us8){ f2bf(v0[0]), f2bf(v0[1]), f2bf(v0[2]), f2bf(v0[3]),
                           f2bf(v1[0]), f2bf(v1[1]), f2bf(v1[2]), f2bf(v1[3]) };
        }
        __syncthreads();   // previous iteration's LDS reads done
#pragma unroll
        for (int p = 0; p < MI; p++) {   // A: direct-to-LDS, 8 rows per chunk
            const int chunk = p * 4 + wid;
            gload16(A + (size_t)(m0 + chunk * 8 + lrow) * K + k0 + lcol, As + chunk * 512);
        }
#pragma unroll
        for (int p = 0; p < 4; p++)
            *(us8*)(Bs + (brow + p * 32) * 72 + bcol) = bv[p];
        __syncthreads();   // drains vmcnt (gload) + lgkm (ds_write)
#pragma unroll
        for (int kk = 0; kk < 2; kk++) {
            us8 af[MI], bf[4];
#pragma unroll
            for (int mi = 0; mi < MI; mi++)
                af[mi] = *(const us8*)(As + (wr * (MI * 16) + mi * 16 + s) * 64 + kk * 32 + g * 8);
#pragma unroll
            for (int ni = 0; ni < 4; ni++)
                bf[ni] = *(const us8*)(Bs + (wc * 64 + ni * 16 + s) * 72 + kk * 32 + g * 8);
#pragma unroll
            for (int mi = 0; mi < MI; mi++)
#pragma unroll
                for (int ni = 0; ni < 4; ni++)
                    acc[mi][ni] = mfma16(af[mi], bf[ni], acc[mi][ni]);
        }
    }
}

// ---------------- QKV projection: X[4096][1024](bf16) x W*[1024][1024]^T(f32) ----------------
// grid 768 = 32 bm x 24 bn; bn selects Wq/Wk/Wv. Q pre-scaled 1/8.
// V blocks: acc -> LDS transpose tile T[128 d][128 t] (reuses As|Bs) -> coalesced us8 to VtG.
__global__ __launch_bounds__(256) void gemm_qkv(
    const unsigned short* __restrict__ X, const float* __restrict__ Wq,
    const float* __restrict__ Wk, const float* __restrict__ Wv,
    unsigned short* __restrict__ Qb, unsigned short* __restrict__ Kb,
    unsigned short* __restrict__ VtG) {
    __shared__ unsigned short S[17408];   // As[128*64]=8192 | Bs[128*72]=9216; V reuse: T[128][136]
    unsigned short* As = S;
    unsigned short* Bs = S + 8192;
    const int bm = blockIdx.x & 31, bn = blockIdx.x >> 5;
    const int m0 = bm * 128;
    const int which = bn >> 3;                 // 0:Q 1:K 2:V
    const int n0 = (bn & 7) * 128;
    const float* W = which == 0 ? Wq : (which == 1 ? Wk : Wv);
    f32x4 acc[4][4];
    gemm_core_m<4>(X, W, 1024, m0, n0, As, Bs, acc);
    const int tid = threadIdx.x, lane = tid & 63, wid = tid >> 6;
    const int g = lane >> 4, s = lane & 15, wr = wid >> 1, wc = wid & 1;
    if (which < 2) {
        unsigned short* dst = which == 0 ? Qb : Kb;
        const float scale = which == 0 ? 0.125f : 1.0f;
#pragma unroll
        for (int mi = 0; mi < 4; mi++)
#pragma unroll
            for (int ni = 0; ni < 4; ni++) {
                int n1 = n0 + wc * 64 + ni * 16 + s;   // 0..1023 within this W
                int hh = n1 >> 6, dd = n1 & 63;
#pragma unroll
                for (int r = 0; r < 4; r++) {
                    int mg = m0 + wr * 64 + mi * 16 + 4 * g + r;  // D row = (lane>>4)*4+reg
                    int bb = mg >> 11, tt = mg & 2047;
                    dst[((size_t)(bb * 16 + hh) * 2048 + tt) * 64 + dd] = f2bf(acc[mi][ni][r] * scale);
                }
            }
    } else {
        // ---- V: transpose in LDS, then coalesced writes along t ----
        __syncthreads();   // all waves done reading As/Bs
        unsigned* T32 = (unsigned*)S;   // T[128][136] shorts = [128][68] dwords
#pragma unroll
        for (int mi = 0; mi < 4; mi++)
#pragma unroll
            for (int ni = 0; ni < 4; ni++) {
                int nl = wc * 64 + ni * 16 + s;                 // local d
                int mlh = ((wr * 64 + mi * 16) >> 1) + 2 * g;   // dword base along t
                T32[nl * 68 + mlh]     = cvt_pk_bf16(acc[mi][ni][0], acc[mi][ni][1]);
                T32[nl * 68 + mlh + 1] = cvt_pk_bf16(acc[mi][ni][2], acc[mi][ni][3]);
            }
        __syncthreads();
        // read-out: full 128 t per row -> 16 d-rows per pass, 8 passes
        const int row = tid >> 4, col8 = (tid & 15) * 8;
        const int bb = m0 >> 11, tt0 = m0 & 2047;
#pragma unroll
        for (int p = 0; p < 8; p++) {
            int nl = row + 16 * p;
            int n1 = n0 + nl, hh = n1 >> 6, dd = n1 & 63;
            us8 v = *(const us8*)(S + nl * 136 + col8);
            *(us8*)(VtG + ((size_t)(bb * 16 + hh) * 64 + dd) * 2048 + tt0 + col8) = v;
        }
    }
}

// ---------------- flash attention (causal), 1024 blocks, XCD-local, balanced ----------------
// bid: bh = bid&31 (bid%8==bh%8 -> head-local XCD L2), j = bid>>5, q4=j&7:
// i = {q4, 15-q4, 16+q4, 31-q4}[j>>3]. Block does q-tile i (64 rows), iters 0..i.
__global__ __launch_bounds__(256) void attn(
    const unsigned short* __restrict__ Qb, const unsigned short* __restrict__ Kb,
    const unsigned short* __restrict__ VtG, unsigned short* __restrict__ Ob) {
    __shared__ unsigned short Ks[64 * 72];  // [k][d]
    __shared__ unsigned short Vt[64 * 72];  // [d][k]
    const int bh = blockIdx.x & 31, j = blockIdx.x >> 5;
    const int q4 = j & 7, sel = j >> 3;
    const int i = sel == 0 ? q4 : (sel == 1 ? 15 - q4 : (sel == 2 ? 16 + q4 : 31 - q4));
    const int b = bh >> 4, h = bh & 15;
    const unsigned short* Qp = Qb + (size_t)bh * 2048 * 64;
    const unsigned short* Kp = Kb + (size_t)bh * 2048 * 64;
    const unsigned short* Vp = VtG + (size_t)bh * 64 * 2048;   // [d][t]
    const int tid = threadIdx.x, lane = tid & 63, wid = tid >> 6;
    const int g = lane >> 4, s = lane & 15;
    const int qb0 = i * 64 + wid * 16;
    const int qg = qb0 + s;
    us8 qf[2];
    qf[0] = *(const us8*)(Qp + (size_t)qg * 64 + g * 8);
    qf[1] = *(const us8*)(Qp + (size_t)qg * 64 + 32 + g * 8);
    float m_run = -3.0e38f, l_run = 0.f;
    f32x4 o_acc[4];
#pragma unroll
    for (int db = 0; db < 4; db++) o_acc[db] = (f32x4){0.f, 0.f, 0.f, 0.f};
    const int srow = tid >> 3, scol = (tid & 7) * 8;   // srow 0..31
    us8 kpre[2], vpre[2];
#pragma unroll
    for (int p = 0; p < 2; p++) {
        kpre[p] = *(const us8*)(Kp + (size_t)(srow + 32 * p) * 64 + scol);
        vpre[p] = *(const us8*)(Vp + (size_t)(srow + 32 * p) * 2048 + scol);
    }
    for (int it = 0; it <= i; ++it) {
        const int kv0 = it * 64;
        __syncthreads();
#pragma unroll
        for (int p = 0; p < 2; p++) {
            *(us8*)(Ks + (srow + 32 * p) * 72 + scol) = kpre[p];
            *(us8*)(Vt + (srow + 32 * p) * 72 + scol) = vpre[p];
        }
        __syncthreads();
        if (it < i) {   // prefetch next tile (overlaps compute below)
            const int nkv0 = kv0 + 64;
#pragma unroll
            for (int p = 0; p < 2; p++) {
                kpre[p] = *(const us8*)(Kp + (size_t)(nkv0 + srow + 32 * p) * 64 + scol);
                vpre[p] = *(const us8*)(Vp + (size_t)(srow + 32 * p) * 2048 + nkv0 + scol);
            }
        }
        float sf[4][4];
        __builtin_amdgcn_s_setprio(1);
#pragma unroll
        for (int f = 0; f < 4; f++) {
            f32x4 a = (f32x4){0.f, 0.f, 0.f, 0.f};
            us8 k0v = *(const us8*)(Ks + (f * 16 + s) * 72 + g * 8);
            us8 k1v = *(const us8*)(Ks + (f * 16 + s) * 72 + 32 + g * 8);
            a = mfma16(k0v, qf[0], a);
            a = mfma16(k1v, qf[1], a);
#pragma unroll
            for (int r = 0; r < 4; r++) sf[f][r] = a[r];
        }
        __builtin_amdgcn_s_setprio(0);
        if (it == i) {   // diagonal tile: mask k > q
#pragma unroll
            for (int f = 0; f < 4; f++)
#pragma unroll
                for (int r = 0; r < 4; r++)
                    if (kv0 + f * 16 + 4 * g + r > qg) sf[f][r] = -3.0e38f;
        }
        // online softmax per q = s, defer-max (skip O-rescale while max growth <= 8)
        float mt = -3.0e38f;
#pragma unroll
        for (int f = 0; f < 4; f++)
#pragma unroll
            for (int r = 0; r < 4; r++) mt = fmaxf(mt, sf[f][r]);
        mt = fmaxf(mt, __shfl_xor(mt, 16));
        mt = fmaxf(mt, __shfl_xor(mt, 32));
        float mnew = m_run;
        if (!__all(mt - m_run <= 8.0f)) {   // wave-uniform
            mnew = fmaxf(m_run, mt);
            float alpha = __builtin_amdgcn_exp2f((m_run - mnew) * LOG2E);
            l_run *= alpha;
            float al[4];
#pragma unroll
            for (int r = 0; r < 4; r++) al[r] = __shfl(alpha, 4 * g + r, 64);
#pragma unroll
            for (int db = 0; db < 4; db++)
#pragma unroll
                for (int r = 0; r < 4; r++) o_acc[db][r] *= al[r];
        }
        float psum = 0.f;
#pragma unroll
        for (int f = 0; f < 4; f++)
#pragma unroll
            for (int r = 0; r < 4; r++) {
                float p = __builtin_amdgcn_exp2f((sf[f][r] - mnew) * LOG2E);
                sf[f][r] = p;
                psum += p;
            }
        psum += __shfl_xor(psum, 16);
        psum += __shfl_xor(psum, 32);
        l_run += psum;
        m_run = mnew;
        // packed redistribute: P (D-layout) -> PV a-frag layout
        unsigned pk[4][2];
#pragma unroll
        for (int f = 0; f < 4; f++)
#pragma unroll
            for (int hh2 = 0; hh2 < 2; hh2++)
                pk[f][hh2] = cvt_pk_bf16(sf[f][2 * hh2], sf[f][2 * hh2 + 1]);
        const int srcA = 32 * (g & 1) + s, srcB = srcA + 16;
        const bool ghi = g >= 2;
        us8 pa[2];
#pragma unroll
        for (int kk = 0; kk < 2; kk++) {
            unsigned e0 = __shfl(pk[kk * 2][0], srcA, 64);
            unsigned e1 = __shfl(pk[kk * 2][1], srcA, 64);
            unsigned e2 = __shfl(pk[kk * 2][0], srcB, 64);
            unsigned e3 = __shfl(pk[kk * 2][1], srcB, 64);
            unsigned o0 = __shfl(pk[kk * 2 + 1][0], srcA, 64);
            unsigned o1 = __shfl(pk[kk * 2 + 1][1], srcA, 64);
            unsigned o2 = __shfl(pk[kk * 2 + 1][0], srcB, 64);
            unsigned o3 = __shfl(pk[kk * 2 + 1][1], srcB, 64);
            u32x4 dw = { ghi ? o0 : e0, ghi ? o1 : e1, ghi ? o2 : e2, ghi ? o3 : e3 };
            pa[kk] = __builtin_bit_cast(us8, dw);
        }
        // PV: O[q][d] += P * V
        __builtin_amdgcn_s_setprio(1);
#pragma unroll
        for (int db = 0; db < 4; db++) {
            const unsigned short* vrow = Vt + (db * 16 + s) * 72;
            us8 vf0 = *(const us8*)(vrow + g * 8);
            o_acc[db] = mfma16(pa[0], vf0, o_acc[db]);
            us8 vf1 = *(const us8*)(vrow + 32 + g * 8);
            o_acc[db] = mfma16(pa[1], vf1, o_acc[db]);
        }
        __builtin_amdgcn_s_setprio(0);
    }
    // epilogue: divide by row sum, write O as [B][T][C] bf16
    float li[4];
#pragma unroll
    for (int r = 0; r < 4; r++) li[r] = __shfl(l_run, 4 * g + r, 64);
#pragma unroll
    for (int db = 0; db < 4; db++)
#pragma unroll
        for (int r = 0; r < 4; r++) {
            int qq = qb0 + 4 * g + r;
            float v = o_acc[db][r] / li[r];
            Ob[((size_t)(b * 2048) + qq) * 1024 + h * 64 + db * 16 + s] = f2bf(v);
        }
}

// ---------------- output projection: O[4096][1024](bf16) x Wc[1024][1024]^T(f32) + bc ----------------
// 64x128 tiles -> grid 512 (2 blocks/CU).
__global__ __launch_bounds__(256) void gemm_out(
    const unsigned short* __restrict__ O, const float* __restrict__ Wc,
    const float* __restrict__ bc, float* __restrict__ out) {
    __shared__ unsigned short As[64 * 64];
    __shared__ unsigned short Bs[128 * 72];
    const int bm = blockIdx.x & 63, bn = blockIdx.x >> 6;   // 64 x 8
    const int m0 = bm * 64, n0 = bn * 128;
    f32x4 acc[2][4];
    gemm_core_m<2>(O, Wc, 1024, m0, n0, As, Bs, acc);
    const int lane = threadIdx.x & 63, wid = threadIdx.x >> 6;
    const int g = lane >> 4, s = lane & 15, wr = wid >> 1, wc = wid & 1;
#pragma unroll
    for (int mi = 0; mi < 2; mi++)
#pragma unroll
        for (int ni = 0; ni < 4; ni++) {
            int ng = n0 + wc * 64 + ni * 16 + s;
            float bias = bc[ng];
#pragma unroll
            for (int r = 0; r < 4; r++) {
                int mg = m0 + wr * 32 + mi * 16 + 4 * g + r;
                out[(size_t)mg * 1024 + ng] = acc[mi][ni][r] + bias;
            }
        }
}

extern "C" void kernel_launch(void* const* d_in, const int* in_sizes, int n_in,
                              void* d_out, int out_size, void* d_ws, size_t ws_size,
                              hipStream_t stream) {
    const float* x  = (const float*)d_in[0];
    const float* Wq = (const float*)d_in[1];
    const float* Wk = (const float*)d_in[2];
    const float* Wv = (const float*)d_in[3];
    const float* Wc = (const float*)d_in[4];
    const float* bc = (const float*)d_in[5];
    float* out = (float*)d_out;

    if (ws_size < 33554432) {
        fill_sentinel<<<(out_size + 255) / 256, 256, 0, stream>>>(out, out_size);
        return;
    }
    char* w = (char*)d_ws;
    unsigned short* Qb  = (unsigned short*)(w);
    unsigned short* Kb  = (unsigned short*)(w + 8388608);
    unsigned short* VtG = (unsigned short*)(w + 16777216);   // [bh][d][t]
    unsigned short* Ob  = (unsigned short*)(w + 25165824);
    unsigned short* xb  = (unsigned short*)d_out;            // dead before gemm_out writes

    cvt_x<<<4096, 256, 0, stream>>>(x, xb);
    gemm_qkv<<<768, 256, 0, stream>>>(xb, Wq, Wk, Wv, Qb, Kb, VtG);
    attn<<<1024, 256, 0, stream>>>(Qb, Kb, VtG, Ob);
    gemm_out<<<512, 256, 0, stream>>>(Ob, Wc, bc, out);
}

// Round 10
// 145.078 us; speedup vs baseline: 1.0387x; 1.0387x over previous
//
#include <hip/hip_runtime.h>
#include <hip/hip_bf16.h>

// Fused MHA: B=2, T=2048, C=1024, H=16, dh=64.
// cvt_x -> qkv GEMM (reg-staged A bf16 + W fp32; V transposed via LDS epilogue)
// -> flash attention (512 uniform paired blocks, XCD-local, defer-max) -> out GEMM.
// ws (32 MiB): Qb | Kb | VtG | Ob. d_out[0,8MB) = x_bf16 scratch (dead before gemm_out).

typedef __attribute__((ext_vector_type(4))) float f32x4;
typedef __attribute__((ext_vector_type(4))) unsigned int u32x4;
typedef __attribute__((ext_vector_type(8))) __bf16 bf16x8;
typedef __attribute__((ext_vector_type(8))) unsigned short us8;
typedef __attribute__((ext_vector_type(4))) unsigned short us4;

#define LOG2E 1.4426950408889634f

__device__ __forceinline__ unsigned short f2bf(float f) {
    unsigned u = __builtin_bit_cast(unsigned, f);
    u += 0x7fffu + ((u >> 16) & 1u);   // round-to-nearest-even
    return (unsigned short)(u >> 16);
}

__device__ __forceinline__ unsigned cvt_pk_bf16(float lo, float hi) {
    unsigned r;
    asm("v_cvt_pk_bf16_f32 %0, %1, %2" : "=v"(r) : "v"(lo), "v"(hi));
    return r;
}

__device__ __forceinline__ f32x4 mfma16(us8 a, us8 b, f32x4 c) {
    return __builtin_amdgcn_mfma_f32_16x16x32_bf16(
        __builtin_bit_cast(bf16x8, a), __builtin_bit_cast(bf16x8, b), c, 0, 0, 0);
}

__global__ __launch_bounds__(256) void fill_sentinel(float* __restrict__ out, int n) {
    int i = blockIdx.x * 256 + threadIdx.x;
    if (i < n) out[i] = 12345.0f;
}

__global__ __launch_bounds__(256) void cvt_x(const float* __restrict__ x,
                                             unsigned short* __restrict__ xb) {
    int idx = (blockIdx.x * 256 + threadIdx.x) * 4;
    f32x4 v = *(const f32x4*)(x + idx);
    us4 o = { f2bf(v[0]), f2bf(v[1]), f2bf(v[2]), f2bf(v[3]) };
    *(us4*)(xb + idx) = o;
}

// ---------------- reg-staged GEMM core: C[m][n] = sum_k A[m][k]*B[n][k] ----------------
// Tile (MI*32)x128, BK=64, 256 threads = 4 waves (2x2); wave does (MI*16)x64.
// A bf16, B fp32->bf16; ALL global loads issued BEFORE barrier-1 (overlap prev MFMA).
// LDS rows padded to 72 shorts (2-way bank alias on b128 = free).
template <int MI>
__device__ __forceinline__ void gemm_core_r(
    const unsigned short* __restrict__ A, const float* __restrict__ Bf,
    int K, int m0, int n0, unsigned short* As, unsigned short* Bs, f32x4 acc[MI][4]) {
    const int tid = threadIdx.x;
    const int lane = tid & 63, wid = tid >> 6;
    const int g = lane >> 4, s = lane & 15;
    const int wr = wid >> 1, wc = wid & 1;
#pragma unroll
    for (int mi = 0; mi < MI; mi++)
#pragma unroll
        for (int ni = 0; ni < 4; ni++) acc[mi][ni] = (f32x4){0.f, 0.f, 0.f, 0.f};
    const int row = tid >> 3, col = (tid & 7) * 8;
    for (int k0 = 0; k0 < K; k0 += 64) {
        us8 av[MI], bv[4];
#pragma unroll
        for (int p = 0; p < MI; p++)
            av[p] = *(const us8*)(A + (size_t)(m0 + row + p * 32) * K + k0 + col);
#pragma unroll
        for (int p = 0; p < 4; p++) {
            size_t boff = (size_t)(n0 + row + p * 32) * K + k0 + col;
            f32x4 v0 = *(const f32x4*)(Bf + boff);
            f32x4 v1 = *(const f32x4*)(Bf + boff + 4);
            bv[p] = (us8){ f2bf(v0[0]), f2bf(v0[1]), f2bf(v0[2]), f2bf(v0[3]),
                           f2bf(v1[0]), f2bf(v1[1]), f2bf(v1[2]), f2bf(v1[3]) };
        }
        __syncthreads();   // previous iteration's LDS reads done
#pragma unroll
        for (int p = 0; p < MI; p++)
            *(us8*)(As + (row + p * 32) * 72 + col) = av[p];
#pragma unroll
        for (int p = 0; p < 4; p++)
            *(us8*)(Bs + (row + p * 32) * 72 + col) = bv[p];
        __syncthreads();
#pragma unroll
        for (int kk = 0; kk < 2; kk++) {
            us8 af[MI], bf[4];
#pragma unroll
            for (int mi = 0; mi < MI; mi++)
                af[mi] = *(const us8*)(As + (wr * (MI * 16) + mi * 16 + s) * 72 + kk * 32 + g * 8);
#pragma unroll
            for (int ni = 0; ni < 4; ni++)
                bf[ni] = *(const us8*)(Bs + (wc * 64 + ni * 16 + s) * 72 + kk * 32 + g * 8);
#pragma unroll
            for (int mi = 0; mi < MI; mi++)
#pragma unroll
                for (int ni = 0; ni < 4; ni++)
                    acc[mi][ni] = mfma16(af[mi], bf[ni], acc[mi][ni]);
        }
    }
}

// ---------------- QKV projection: X[4096][1024](bf16) x W*[1024][1024]^T(f32) ----------------
// grid 768 = 32 bm x 24 bn; bn selects Wq/Wk/Wv. Q pre-scaled 1/8.
// V blocks: acc -> LDS transpose tile T[128 d][128 t] (reuses As|Bs) -> coalesced us8 to VtG.
__global__ __launch_bounds__(256) void gemm_qkv(
    const unsigned short* __restrict__ X, const float* __restrict__ Wq,
    const float* __restrict__ Wk, const float* __restrict__ Wv,
    unsigned short* __restrict__ Qb, unsigned short* __restrict__ Kb,
    unsigned short* __restrict__ VtG) {
    __shared__ unsigned short S[18432];   // As[128*72] | Bs[128*72]; V reuse: T[128][136]=17408
    unsigned short* As = S;
    unsigned short* Bs = S + 9216;
    const int bm = blockIdx.x & 31, bn = blockIdx.x >> 5;
    const int m0 = bm * 128;
    const int which = bn >> 3;                 // 0:Q 1:K 2:V
    const int n0 = (bn & 7) * 128;
    const float* W = which == 0 ? Wq : (which == 1 ? Wk : Wv);
    f32x4 acc[4][4];
    gemm_core_r<4>(X, W, 1024, m0, n0, As, Bs, acc);
    const int tid = threadIdx.x, lane = tid & 63, wid = tid >> 6;
    const int g = lane >> 4, s = lane & 15, wr = wid >> 1, wc = wid & 1;
    if (which < 2) {
        unsigned short* dst = which == 0 ? Qb : Kb;
        const float scale = which == 0 ? 0.125f : 1.0f;
#pragma unroll
        for (int mi = 0; mi < 4; mi++)
#pragma unroll
            for (int ni = 0; ni < 4; ni++) {
                int n1 = n0 + wc * 64 + ni * 16 + s;   // 0..1023 within this W
                int hh = n1 >> 6, dd = n1 & 63;
#pragma unroll
                for (int r = 0; r < 4; r++) {
                    int mg = m0 + wr * 64 + mi * 16 + 4 * g + r;  // D row = (lane>>4)*4+reg
                    int bb = mg >> 11, tt = mg & 2047;
                    dst[((size_t)(bb * 16 + hh) * 2048 + tt) * 64 + dd] = f2bf(acc[mi][ni][r] * scale);
                }
            }
    } else {
        // ---- V: transpose in LDS, then coalesced writes along t ----
        __syncthreads();   // all waves done reading As/Bs
        unsigned* T32 = (unsigned*)S;   // T[128][136] shorts = [128][68] dwords
#pragma unroll
        for (int mi = 0; mi < 4; mi++)
#pragma unroll
            for (int ni = 0; ni < 4; ni++) {
                int nl = wc * 64 + ni * 16 + s;                 // local d
                int mlh = ((wr * 64 + mi * 16) >> 1) + 2 * g;   // dword base along t
                T32[nl * 68 + mlh]     = cvt_pk_bf16(acc[mi][ni][0], acc[mi][ni][1]);
                T32[nl * 68 + mlh + 1] = cvt_pk_bf16(acc[mi][ni][2], acc[mi][ni][3]);
            }
        __syncthreads();
        // read-out: full 128 t per row -> 16 d-rows per pass, 8 passes
        const int row = tid >> 4, col8 = (tid & 15) * 8;
        const int bb = m0 >> 11, tt0 = m0 & 2047;
#pragma unroll
        for (int p = 0; p < 8; p++) {
            int nl = row + 16 * p;
            int n1 = n0 + nl, hh = n1 >> 6, dd = n1 & 63;
            us8 v = *(const us8*)(S + nl * 136 + col8);
            *(us8*)(VtG + ((size_t)(bb * 16 + hh) * 64 + dd) * 2048 + tt0 + col8) = v;
        }
    }
}

// ---------------- flash attention (causal), 512 uniform paired blocks, XCD-local ----------------
// bh = bid&31 (bid%8==bh%8 -> all blocks of a head on one XCD), i = bid>>5 (0..15).
// Block does q-tile A=i (iters 0..i) then B=31-i (iters i+1..32): 33 iters EVERY block
// -> 2 identical-length blocks/CU, no occupancy tail. Defer-max; packed redistribute.
#define ATTN_EPILOGUE(QB0, OA, LR)                                              \
    {                                                                           \
        float li[4];                                                            \
        _Pragma("unroll") for (int r = 0; r < 4; r++)                           \
            li[r] = __shfl((LR), 4 * g + r, 64);                                \
        _Pragma("unroll") for (int db = 0; db < 4; db++)                        \
            _Pragma("unroll") for (int r = 0; r < 4; r++) {                     \
                int qq = (QB0) + 4 * g + r;                                     \
                float v = (OA)[db][r] / li[r];                                  \
                Ob[((size_t)(b * 2048) + qq) * 1024 + h * 64 + db * 16 + s] = f2bf(v); \
            }                                                                   \
    }

__global__ __launch_bounds__(256) void attn(
    const unsigned short* __restrict__ Qb, const unsigned short* __restrict__ Kb,
    const unsigned short* __restrict__ VtG, unsigned short* __restrict__ Ob) {
    __shared__ unsigned short Ks[64 * 72];  // [k][d]
    __shared__ unsigned short Vt[64 * 72];  // [d][k]
    const int bh = blockIdx.x & 31, i = blockIdx.x >> 5;   // i in 0..15
    const int b = bh >> 4, h = bh & 15;
    const unsigned short* Qp = Qb + (size_t)bh * 2048 * 64;
    const unsigned short* Kp = Kb + (size_t)bh * 2048 * 64;
    const unsigned short* Vp = VtG + (size_t)bh * 64 * 2048;   // [d][t]
    const int tid = threadIdx.x, lane = tid & 63, wid = tid >> 6;
    const int g = lane >> 4, s = lane & 15;
    const int qbA = i * 64 + wid * 16;          // tile A
    const int qbB = (31 - i) * 64 + wid * 16;   // tile B
    const int qgA = qbA + s, qgB = qbB + s;
    us8 qfA[2], qfB[2];
    qfA[0] = *(const us8*)(Qp + (size_t)qgA * 64 + g * 8);
    qfA[1] = *(const us8*)(Qp + (size_t)qgA * 64 + 32 + g * 8);
    qfB[0] = *(const us8*)(Qp + (size_t)qgB * 64 + g * 8);
    qfB[1] = *(const us8*)(Qp + (size_t)qgB * 64 + 32 + g * 8);
    float m_run = -3.0e38f, l_run = 0.f;
    f32x4 o_acc[4];
#pragma unroll
    for (int db = 0; db < 4; db++) o_acc[db] = (f32x4){0.f, 0.f, 0.f, 0.f};
    const int srow = tid >> 3, scol = (tid & 7) * 8;   // srow 0..31
    us8 kpre[2], vpre[2];
#pragma unroll
    for (int p = 0; p < 2; p++) {
        kpre[p] = *(const us8*)(Kp + (size_t)(srow + 32 * p) * 64 + scol);
        vpre[p] = *(const us8*)(Vp + (size_t)(srow + 32 * p) * 2048 + scol);
    }
    for (int it = 0; it <= 32; ++it) {
        const bool qsel = it > i;
        const int kv0 = (qsel ? it - i - 1 : it) * 64;
        __syncthreads();
#pragma unroll
        for (int p = 0; p < 2; p++) {
            *(us8*)(Ks + (srow + 32 * p) * 72 + scol) = kpre[p];
            *(us8*)(Vt + (srow + 32 * p) * 72 + scol) = vpre[p];
        }
        __syncthreads();
        if (it < 32) {   // prefetch next tile (overlaps compute below)
            const int nx = it + 1;
            const int nkv0 = (nx > i ? nx - i - 1 : nx) * 64;
#pragma unroll
            for (int p = 0; p < 2; p++) {
                kpre[p] = *(const us8*)(Kp + (size_t)(nkv0 + srow + 32 * p) * 64 + scol);
                vpre[p] = *(const us8*)(Vp + (size_t)(srow + 32 * p) * 2048 + nkv0 + scol);
            }
        }
        if (it == i + 1) {   // tile A finished: emit + reset stats
            ATTN_EPILOGUE(qbA, o_acc, l_run);
            m_run = -3.0e38f; l_run = 0.f;
#pragma unroll
            for (int db = 0; db < 4; db++) o_acc[db] = (f32x4){0.f, 0.f, 0.f, 0.f};
        }
        const int qg = qsel ? qgB : qgA;
        const us8* qf = qsel ? qfB : qfA;
        float sf[4][4];
        __builtin_amdgcn_s_setprio(1);
#pragma unroll
        for (int f = 0; f < 4; f++) {
            f32x4 a = (f32x4){0.f, 0.f, 0.f, 0.f};
            us8 k0v = *(const us8*)(Ks + (f * 16 + s) * 72 + g * 8);
            us8 k1v = *(const us8*)(Ks + (f * 16 + s) * 72 + 32 + g * 8);
            a = mfma16(k0v, qf[0], a);
            a = mfma16(k1v, qf[1], a);
#pragma unroll
            for (int r = 0; r < 4; r++) sf[f][r] = a[r];
        }
        __builtin_amdgcn_s_setprio(0);
        const bool diag = qsel ? (it == 32) : (it == i);
        if (diag) {   // diagonal tile: mask k > q
#pragma unroll
            for (int f = 0; f < 4; f++)
#pragma unroll
                for (int r = 0; r < 4; r++)
                    if (kv0 + f * 16 + 4 * g + r > qg) sf[f][r] = -3.0e38f;
        }
        // online softmax per q = s, defer-max (skip O-rescale while max growth <= 8)
        float mt = -3.0e38f;
#pragma unroll
        for (int f = 0; f < 4; f++)
#pragma unroll
            for (int r = 0; r < 4; r++) mt = fmaxf(mt, sf[f][r]);
        mt = fmaxf(mt, __shfl_xor(mt, 16));
        mt = fmaxf(mt, __shfl_xor(mt, 32));
        float mnew = m_run;
        if (!__all(mt - m_run <= 8.0f)) {   // wave-uniform
            mnew = fmaxf(m_run, mt);
            float alpha = __builtin_amdgcn_exp2f((m_run - mnew) * LOG2E);
            l_run *= alpha;
            float al[4];
#pragma unroll
            for (int r = 0; r < 4; r++) al[r] = __shfl(alpha, 4 * g + r, 64);
#pragma unroll
            for (int db = 0; db < 4; db++)
#pragma unroll
                for (int r = 0; r < 4; r++) o_acc[db][r] *= al[r];
        }
        float psum = 0.f;
#pragma unroll
        for (int f = 0; f < 4; f++)
#pragma unroll
            for (int r = 0; r < 4; r++) {
                float p = __builtin_amdgcn_exp2f((sf[f][r] - mnew) * LOG2E);
                sf[f][r] = p;
                psum += p;
            }
        psum += __shfl_xor(psum, 16);
        psum += __shfl_xor(psum, 32);
        l_run += psum;
        m_run = mnew;
        // packed redistribute: P (D-layout) -> PV a-frag layout
        unsigned pk[4][2];
#pragma unroll
        for (int f = 0; f < 4; f++)
#pragma unroll
            for (int hh2 = 0; hh2 < 2; hh2++)
                pk[f][hh2] = cvt_pk_bf16(sf[f][2 * hh2], sf[f][2 * hh2 + 1]);
        const int srcA = 32 * (g & 1) + s, srcB = srcA + 16;
        const bool ghi = g >= 2;
        us8 pa[2];
#pragma unroll
        for (int kk = 0; kk < 2; kk++) {
            unsigned e0 = __shfl(pk[kk * 2][0], srcA, 64);
            unsigned e1 = __shfl(pk[kk * 2][1], srcA, 64);
            unsigned e2 = __shfl(pk[kk * 2][0], srcB, 64);
            unsigned e3 = __shfl(pk[kk * 2][1], srcB, 64);
            unsigned o0 = __shfl(pk[kk * 2 + 1][0], srcA, 64);
            unsigned o1 = __shfl(pk[kk * 2 + 1][1], srcA, 64);
            unsigned o2 = __shfl(pk[kk * 2 + 1][0], srcB, 64);
            unsigned o3 = __shfl(pk[kk * 2 + 1][1], srcB, 64);
            u32x4 dw = { ghi ? o0 : e0, ghi ? o1 : e1, ghi ? o2 : e2, ghi ? o3 : e3 };
            pa[kk] = __builtin_bit_cast(us8, dw);
        }
        // PV: O[q][d] += P * V
        __builtin_amdgcn_s_setprio(1);
#pragma unroll
        for (int db = 0; db < 4; db++) {
            const unsigned short* vrow = Vt + (db * 16 + s) * 72;
            us8 vf0 = *(const us8*)(vrow + g * 8);
            o_acc[db] = mfma16(pa[0], vf0, o_acc[db]);
            us8 vf1 = *(const us8*)(vrow + 32 + g * 8);
            o_acc[db] = mfma16(pa[1], vf1, o_acc[db]);
        }
        __builtin_amdgcn_s_setprio(0);
    }
    ATTN_EPILOGUE(qbB, o_acc, l_run);
}

// ---------------- output projection: O[4096][1024](bf16) x Wc[1024][1024]^T(f32) + bc ----------------
// 64x128 tiles -> grid 512 (2 blocks/CU).
__global__ __launch_bounds__(256) void gemm_out(
    const unsigned short* __restrict__ O, const float* __restrict__ Wc,
    const float* __restrict__ bc, float* __restrict__ out) {
    __shared__ unsigned short As[64 * 72];
    __shared__ unsigned short Bs[128 * 72];
    const int bm = blockIdx.x & 63, bn = blockIdx.x >> 6;   // 64 x 8
    const int m0 = bm * 64, n0 = bn * 128;
    f32x4 acc[2][4];
    gemm_core_r<2>(O, Wc, 1024, m0, n0, As, Bs, acc);
    const int lane = threadIdx.x & 63, wid = threadIdx.x >> 6;
    const int g = lane >> 4, s = lane & 15, wr = wid >> 1, wc = wid & 1;
#pragma unroll
    for (int mi = 0; mi < 2; mi++)
#pragma unroll
        for (int ni = 0; ni < 4; ni++) {
            int ng = n0 + wc * 64 + ni * 16 + s;
            float bias = bc[ng];
#pragma unroll
            for (int r = 0; r < 4; r++) {
                int mg = m0 + wr * 32 + mi * 16 + 4 * g + r;
                out[(size_t)mg * 1024 + ng] = acc[mi][ni][r] + bias;
            }
        }
}

extern "C" void kernel_launch(void* const* d_in, const int* in_sizes, int n_in,
                              void* d_out, int out_size, void* d_ws, size_t ws_size,
                              hipStream_t stream) {
    const float* x  = (const float*)d_in[0];
    const float* Wq = (const float*)d_in[1];
    const float* Wk = (const float*)d_in[2];
    const float* Wv = (const float*)d_in[3];
    const float* Wc = (const float*)d_in[4];
    const float* bc = (const float*)d_in[5];
    float* out = (float*)d_out;

    if (ws_size < 33554432) {
        fill_sentinel<<<(out_size + 255) / 256, 256, 0, stream>>>(out, out_size);
        return;
    }
    char* w = (char*)d_ws;
    unsigned short* Qb  = (unsigned short*)(w);
    unsigned short* Kb  = (unsigned short*)(w + 8388608);
    unsigned short* VtG = (unsigned short*)(w + 16777216);   // [bh][d][t]
    unsigned short* Ob  = (unsigned short*)(w + 25165824);
    unsigned short* xb  = (unsigned short*)d_out;            // dead before gemm_out writes

    cvt_x<<<4096, 256, 0, stream>>>(x, xb);
    gemm_qkv<<<768, 256, 0, stream>>>(xb, Wq, Wk, Wv, Qb, Kb, VtG);
    attn<<<512, 256, 0, stream>>>(Qb, Kb, VtG, Ob);
    gemm_out<<<512, 256, 0, stream>>>(Ob, Wc, bc, out);
}

// Round 11
// 123.329 us; speedup vs baseline: 1.2219x; 1.1763x over previous
//
#include <hip/hip_runtime.h>
#include <hip/hip_bf16.h>

// Fused MHA: B=2, T=2048, C=1024, H=16, dh=64.
// cvt_xw -> qkv GEMM (both-bf16 reg-staged, XCD-tiled; V transposed via LDS epilogue)
// -> flash attention (512 uniform paired blocks, XCD-local, 1-barrier dbuf, defer-max)
// -> cvt_wc -> out GEMM (both-bf16, XCD-tiled).
// ws (32 MiB): Qb | Kb | VtG | Ob; Wc_bf16 reuses Qb region after attn.
// d_out scratch: xb [0,8MB) + wqkvb [8,14MB), dead before gemm_out writes out.

typedef __attribute__((ext_vector_type(4))) float f32x4;
typedef __attribute__((ext_vector_type(4))) unsigned int u32x4;
typedef __attribute__((ext_vector_type(8))) __bf16 bf16x8;
typedef __attribute__((ext_vector_type(8))) unsigned short us8;
typedef __attribute__((ext_vector_type(4))) unsigned short us4;

#define LOG2E 1.4426950408889634f

__device__ __forceinline__ unsigned short f2bf(float f) {
    unsigned u = __builtin_bit_cast(unsigned, f);
    u += 0x7fffu + ((u >> 16) & 1u);   // round-to-nearest-even
    return (unsigned short)(u >> 16);
}

__device__ __forceinline__ unsigned cvt_pk_bf16(float lo, float hi) {
    unsigned r;
    asm("v_cvt_pk_bf16_f32 %0, %1, %2" : "=v"(r) : "v"(lo), "v"(hi));
    return r;
}

__device__ __forceinline__ f32x4 mfma16(us8 a, us8 b, f32x4 c) {
    return __builtin_amdgcn_mfma_f32_16x16x32_bf16(
        __builtin_bit_cast(bf16x8, a), __builtin_bit_cast(bf16x8, b), c, 0, 0, 0);
}

__global__ __launch_bounds__(256) void fill_sentinel(float* __restrict__ out, int n) {
    int i = blockIdx.x * 256 + threadIdx.x;
    if (i < n) out[i] = 12345.0f;
}

// ---- convert x (4,194,304) + Wq|Wk|Wv (3x1,048,576) fp32 -> bf16. 7168 blocks x 256 x 4.
__global__ __launch_bounds__(256) void cvt_xw(
    const float* __restrict__ x, const float* __restrict__ wq,
    const float* __restrict__ wk, const float* __restrict__ wv,
    unsigned short* __restrict__ xb, unsigned short* __restrict__ wqkvb) {
    long i = (long)(blockIdx.x * 256 + threadIdx.x) * 4;
    const float* src; unsigned short* dst; long off;
    if (i < 4194304L)      { src = x;  dst = xb;              off = i; }
    else if (i < 5242880L) { src = wq; dst = wqkvb;           off = i - 4194304L; }
    else if (i < 6291456L) { src = wk; dst = wqkvb + 1048576; off = i - 5242880L; }
    else                   { src = wv; dst = wqkvb + 2097152; off = i - 6291456L; }
    f32x4 v = *(const f32x4*)(src + off);
    us4 o = { f2bf(v[0]), f2bf(v[1]), f2bf(v[2]), f2bf(v[3]) };
    *(us4*)(dst + off) = o;
}

__global__ __launch_bounds__(256) void cvt_wc(const float* __restrict__ wc,
                                              unsigned short* __restrict__ wcb) {
    int idx = (blockIdx.x * 256 + threadIdx.x) * 4;
    f32x4 v = *(const f32x4*)(wc + idx);
    us4 o = { f2bf(v[0]), f2bf(v[1]), f2bf(v[2]), f2bf(v[3]) };
    *(us4*)(wcb + idx) = o;
}

// ---------------- both-bf16 reg-staged GEMM core: C[m][n] = sum_k A[m][k]*B[n][k] ----------------
// Tile (MI*32)x128, BK=64, 256 threads = 4 waves (2x2); wave does (MI*16)x64.
// ALL global loads issued BEFORE barrier-1 (overlap prev MFMA). LDS pad 72 (2-way = free).
template <int MI>
__device__ __forceinline__ void gemm_core_bb(
    const unsigned short* __restrict__ A, const unsigned short* __restrict__ B,
    int K, int m0, int n0, unsigned short* As, unsigned short* Bs, f32x4 acc[MI][4]) {
    const int tid = threadIdx.x;
    const int lane = tid & 63, wid = tid >> 6;
    const int g = lane >> 4, s = lane & 15;
    const int wr = wid >> 1, wc = wid & 1;
#pragma unroll
    for (int mi = 0; mi < MI; mi++)
#pragma unroll
        for (int ni = 0; ni < 4; ni++) acc[mi][ni] = (f32x4){0.f, 0.f, 0.f, 0.f};
    const int row = tid >> 3, col = (tid & 7) * 8;
    for (int k0 = 0; k0 < K; k0 += 64) {
        us8 av[MI], bv[4];
#pragma unroll
        for (int p = 0; p < MI; p++)
            av[p] = *(const us8*)(A + (size_t)(m0 + row + p * 32) * K + k0 + col);
#pragma unroll
        for (int p = 0; p < 4; p++)
            bv[p] = *(const us8*)(B + (size_t)(n0 + row + p * 32) * K + k0 + col);
        __syncthreads();   // previous iteration's LDS reads done
#pragma unroll
        for (int p = 0; p < MI; p++)
            *(us8*)(As + (row + p * 32) * 72 + col) = av[p];
#pragma unroll
        for (int p = 0; p < 4; p++)
            *(us8*)(Bs + (row + p * 32) * 72 + col) = bv[p];
        __syncthreads();
#pragma unroll
        for (int kk = 0; kk < 2; kk++) {
            us8 af[MI], bf[4];
#pragma unroll
            for (int mi = 0; mi < MI; mi++)
                af[mi] = *(const us8*)(As + (wr * (MI * 16) + mi * 16 + s) * 72 + kk * 32 + g * 8);
#pragma unroll
            for (int ni = 0; ni < 4; ni++)
                bf[ni] = *(const us8*)(Bs + (wc * 64 + ni * 16 + s) * 72 + kk * 32 + g * 8);
#pragma unroll
            for (int mi = 0; mi < MI; mi++)
#pragma unroll
                for (int ni = 0; ni < 4; ni++)
                    acc[mi][ni] = mfma16(af[mi], bf[ni], acc[mi][ni]);
        }
    }
}

// ---------------- QKV projection: X[4096][1024] x Wqkv[3072][1024]^T (both bf16) ----------------
// XCD-tiled: xcd = bid&7 -> (bmg = xcd&3, bng = xcd>>2); per XCD 8 bm x 12 bnl
// -> L2 working set ~2MB X + 3MB W. Q pre-scaled 1/8; V transposed via LDS epilogue.
__global__ __launch_bounds__(256) void gemm_qkv(
    const unsigned short* __restrict__ X, const unsigned short* __restrict__ Wb,
    unsigned short* __restrict__ Qb, unsigned short* __restrict__ Kb,
    unsigned short* __restrict__ VtG) {
    __shared__ unsigned short S[18432];   // As[128*72] | Bs[128*72]; V reuse: T[128][136]=17408
    unsigned short* As = S;
    unsigned short* Bs = S + 9216;
    const int bid = blockIdx.x;
    const int xcd = bid & 7, idx = bid >> 3;               // idx 0..95
    const int bm  = (xcd & 3) * 8 + (idx & 7);             // 0..31
    const int bnl = (xcd >> 2) * 12 + (idx >> 3);          // 0..23
    const int m0 = bm * 128;
    const int which = bnl >> 3;                            // 0:Q 1:K 2:V
    const int n0 = (bnl & 7) * 128;
    const unsigned short* W = Wb + (size_t)which * 1048576;
    f32x4 acc[4][4];
    gemm_core_bb<4>(X, W, 1024, m0, n0, As, Bs, acc);
    const int tid = threadIdx.x, lane = tid & 63, wid = tid >> 6;
    const int g = lane >> 4, s = lane & 15, wr = wid >> 1, wc = wid & 1;
    if (which < 2) {
        unsigned short* dst = which == 0 ? Qb : Kb;
        const float scale = which == 0 ? 0.125f : 1.0f;
#pragma unroll
        for (int mi = 0; mi < 4; mi++)
#pragma unroll
            for (int ni = 0; ni < 4; ni++) {
                int n1 = n0 + wc * 64 + ni * 16 + s;   // 0..1023 within this W
                int hh = n1 >> 6, dd = n1 & 63;
#pragma unroll
                for (int r = 0; r < 4; r++) {
                    int mg = m0 + wr * 64 + mi * 16 + 4 * g + r;  // D row = (lane>>4)*4+reg
                    int bb = mg >> 11, tt = mg & 2047;
                    dst[((size_t)(bb * 16 + hh) * 2048 + tt) * 64 + dd] = f2bf(acc[mi][ni][r] * scale);
                }
            }
    } else {
        // ---- V: transpose in LDS, then coalesced writes along t ----
        __syncthreads();   // all waves done reading As/Bs
        unsigned* T32 = (unsigned*)S;   // T[128][136] shorts = [128][68] dwords
#pragma unroll
        for (int mi = 0; mi < 4; mi++)
#pragma unroll
            for (int ni = 0; ni < 4; ni++) {
                int nl = wc * 64 + ni * 16 + s;                 // local d
                int mlh = ((wr * 64 + mi * 16) >> 1) + 2 * g;   // dword base along t
                T32[nl * 68 + mlh]     = cvt_pk_bf16(acc[mi][ni][0], acc[mi][ni][1]);
                T32[nl * 68 + mlh + 1] = cvt_pk_bf16(acc[mi][ni][2], acc[mi][ni][3]);
            }
        __syncthreads();
        // read-out: full 128 t per row -> 16 d-rows per pass, 8 passes
        const int row = tid >> 4, col8 = (tid & 15) * 8;
        const int bb = m0 >> 11, tt0 = m0 & 2047;
#pragma unroll
        for (int p = 0; p < 8; p++) {
            int nl = row + 16 * p;
            int n1 = n0 + nl, hh = n1 >> 6, dd = n1 & 63;
            us8 v = *(const us8*)(S + nl * 136 + col8);
            *(us8*)(VtG + ((size_t)(bb * 16 + hh) * 64 + dd) * 2048 + tt0 + col8) = v;
        }
    }
}

// ---------------- flash attention (causal), 512 uniform paired blocks, XCD-local ----------------
// bh = bid&31 (bid%8==bh%8 -> all blocks of a head on one XCD), i = bid>>5 (0..15).
// Block does q-tile A=i (iters 0..i) then B=31-i (iters i+1..32): 33 iters EVERY block.
// Double-buffered K/V LDS -> ONE barrier per iteration; prefetch distance 2.
#define ATTN_EPILOGUE(QB0, OA, LR)                                              \
    {                                                                           \
        float li[4];                                                            \
        _Pragma("unroll") for (int r = 0; r < 4; r++)                           \
            li[r] = __shfl((LR), 4 * g + r, 64);                                \
        _Pragma("unroll") for (int db = 0; db < 4; db++)                        \
            _Pragma("unroll") for (int r = 0; r < 4; r++) {                     \
                int qq = (QB0) + 4 * g + r;                                     \
                float v = (OA)[db][r] / li[r];                                  \
                Ob[((size_t)(b * 2048) + qq) * 1024 + h * 64 + db * 16 + s] = f2bf(v); \
            }                                                                   \
    }

__global__ __launch_bounds__(256) void attn(
    const unsigned short* __restrict__ Qb, const unsigned short* __restrict__ Kb,
    const unsigned short* __restrict__ VtG, unsigned short* __restrict__ Ob) {
    __shared__ unsigned short Ks[2][64 * 72];  // [k][d]
    __shared__ unsigned short Vt[2][64 * 72];  // [d][k]
    const int bh = blockIdx.x & 31, i = blockIdx.x >> 5;   // i in 0..15
    const int b = bh >> 4, h = bh & 15;
    const unsigned short* Qp = Qb + (size_t)bh * 2048 * 64;
    const unsigned short* Kp = Kb + (size_t)bh * 2048 * 64;
    const unsigned short* Vp = VtG + (size_t)bh * 64 * 2048;   // [d][t]
    const int tid = threadIdx.x, lane = tid & 63, wid = tid >> 6;
    const int g = lane >> 4, s = lane & 15;
    const int qbA = i * 64 + wid * 16;          // tile A
    const int qbB = (31 - i) * 64 + wid * 16;   // tile B
    const int qgA = qbA + s, qgB = qbB + s;
    us8 qfA[2], qfB[2];
    qfA[0] = *(const us8*)(Qp + (size_t)qgA * 64 + g * 8);
    qfA[1] = *(const us8*)(Qp + (size_t)qgA * 64 + 32 + g * 8);
    qfB[0] = *(const us8*)(Qp + (size_t)qgB * 64 + g * 8);
    qfB[1] = *(const us8*)(Qp + (size_t)qgB * 64 + 32 + g * 8);
    float m_run = -3.0e38f, l_run = 0.f;
    f32x4 o_acc[4];
#pragma unroll
    for (int db = 0; db < 4; db++) o_acc[db] = (f32x4){0.f, 0.f, 0.f, 0.f};
    const int srow = tid >> 3, scol = (tid & 7) * 8;   // srow 0..31
    auto tileoff = [&](int jj) { return (jj <= i ? jj : jj - i - 1) * 64; };
    us8 kpre[2], vpre[2];
    // stage tile 0 directly
#pragma unroll
    for (int p = 0; p < 2; p++) {
        kpre[p] = *(const us8*)(Kp + (size_t)(srow + 32 * p) * 64 + scol);
        vpre[p] = *(const us8*)(Vp + (size_t)(srow + 32 * p) * 2048 + scol);
    }
#pragma unroll
    for (int p = 0; p < 2; p++) {
        *(us8*)(&Ks[0][(srow + 32 * p) * 72 + scol]) = kpre[p];
        *(us8*)(&Vt[0][(srow + 32 * p) * 72 + scol]) = vpre[p];
    }
    {   // prefetch tile 1
        const int nk = tileoff(1);
#pragma unroll
        for (int p = 0; p < 2; p++) {
            kpre[p] = *(const us8*)(Kp + (size_t)(nk + srow + 32 * p) * 64 + scol);
            vpre[p] = *(const us8*)(Vp + (size_t)(srow + 32 * p) * 2048 + nk + scol);
        }
    }
    int cur = 0;
    for (int it = 0; it <= 32; ++it) {
        __syncthreads();   // buf[cur] writes visible; prior reads of buf[cur^1] done
        if (it < 32) {     // stage tile it+1 into the other buffer
#pragma unroll
            for (int p = 0; p < 2; p++) {
                *(us8*)(&Ks[cur ^ 1][(srow + 32 * p) * 72 + scol]) = kpre[p];
                *(us8*)(&Vt[cur ^ 1][(srow + 32 * p) * 72 + scol]) = vpre[p];
            }
            if (it < 31) {   // prefetch tile it+2
                const int nk = tileoff(it + 2);
#pragma unroll
                for (int p = 0; p < 2; p++) {
                    kpre[p] = *(const us8*)(Kp + (size_t)(nk + srow + 32 * p) * 64 + scol);
                    vpre[p] = *(const us8*)(Vp + (size_t)(srow + 32 * p) * 2048 + nk + scol);
                }
            }
        }
        if (it == i + 1) {   // tile A finished: emit + reset stats
            ATTN_EPILOGUE(qbA, o_acc, l_run);
            m_run = -3.0e38f; l_run = 0.f;
#pragma unroll
            for (int db = 0; db < 4; db++) o_acc[db] = (f32x4){0.f, 0.f, 0.f, 0.f};
        }
        const bool qsel = it > i;
        const int kv0 = tileoff(it);
        const int qg = qsel ? qgB : qgA;
        const us8* qf = qsel ? qfB : qfA;
        const unsigned short* Kc = Ks[cur];
        const unsigned short* Vc = Vt[cur];
        float sf[4][4];
        __builtin_amdgcn_s_setprio(1);
#pragma unroll
        for (int f = 0; f < 4; f++) {
            f32x4 a = (f32x4){0.f, 0.f, 0.f, 0.f};
            us8 k0v = *(const us8*)(Kc + (f * 16 + s) * 72 + g * 8);
            us8 k1v = *(const us8*)(Kc + (f * 16 + s) * 72 + 32 + g * 8);
            a = mfma16(k0v, qf[0], a);
            a = mfma16(k1v, qf[1], a);
#pragma unroll
            for (int r = 0; r < 4; r++) sf[f][r] = a[r];
        }
        __builtin_amdgcn_s_setprio(0);
        const bool diag = qsel ? (it == 32) : (it == i);
        if (diag) {   // diagonal tile: mask k > q
#pragma unroll
            for (int f = 0; f < 4; f++)
#pragma unroll
                for (int r = 0; r < 4; r++)
                    if (kv0 + f * 16 + 4 * g + r > qg) sf[f][r] = -3.0e38f;
        }
        // online softmax per q = s, defer-max (skip O-rescale while max growth <= 8)
        float mt = -3.0e38f;
#pragma unroll
        for (int f = 0; f < 4; f++)
#pragma unroll
            for (int r = 0; r < 4; r++) mt = fmaxf(mt, sf[f][r]);
        mt = fmaxf(mt, __shfl_xor(mt, 16));
        mt = fmaxf(mt, __shfl_xor(mt, 32));
        float mnew = m_run;
        if (!__all(mt - m_run <= 8.0f)) {   // wave-uniform
            mnew = fmaxf(m_run, mt);
            float alpha = __builtin_amdgcn_exp2f((m_run - mnew) * LOG2E);
            l_run *= alpha;
            float al[4];
#pragma unroll
            for (int r = 0; r < 4; r++) al[r] = __shfl(alpha, 4 * g + r, 64);
#pragma unroll
            for (int db = 0; db < 4; db++)
#pragma unroll
                for (int r = 0; r < 4; r++) o_acc[db][r] *= al[r];
        }
        float psum = 0.f;
#pragma unroll
        for (int f = 0; f < 4; f++)
#pragma unroll
            for (int r = 0; r < 4; r++) {
                float p = __builtin_amdgcn_exp2f((sf[f][r] - mnew) * LOG2E);
                sf[f][r] = p;
                psum += p;
            }
        psum += __shfl_xor(psum, 16);
        psum += __shfl_xor(psum, 32);
        l_run += psum;
        m_run = mnew;
        // packed redistribute: P (D-layout) -> PV a-frag layout
        unsigned pk[4][2];
#pragma unroll
        for (int f = 0; f < 4; f++)
#pragma unroll
            for (int hh2 = 0; hh2 < 2; hh2++)
                pk[f][hh2] = cvt_pk_bf16(sf[f][2 * hh2], sf[f][2 * hh2 + 1]);
        const int srcA = 32 * (g & 1) + s, srcB = srcA + 16;
        const bool ghi = g >= 2;
        us8 pa[2];
#pragma unroll
        for (int kk = 0; kk < 2; kk++) {
            unsigned e0 = __shfl(pk[kk * 2][0], srcA, 64);
            unsigned e1 = __shfl(pk[kk * 2][1], srcA, 64);
            unsigned e2 = __shfl(pk[kk * 2][0], srcB, 64);
            unsigned e3 = __shfl(pk[kk * 2][1], srcB, 64);
            unsigned o0 = __shfl(pk[kk * 2 + 1][0], srcA, 64);
            unsigned o1 = __shfl(pk[kk * 2 + 1][1], srcA, 64);
            unsigned o2 = __shfl(pk[kk * 2 + 1][0], srcB, 64);
            unsigned o3 = __shfl(pk[kk * 2 + 1][1], srcB, 64);
            u32x4 dw = { ghi ? o0 : e0, ghi ? o1 : e1, ghi ? o2 : e2, ghi ? o3 : e3 };
            pa[kk] = __builtin_bit_cast(us8, dw);
        }
        // PV: O[q][d] += P * V
        __builtin_amdgcn_s_setprio(1);
#pragma unroll
        for (int db = 0; db < 4; db++) {
            const unsigned short* vrow = Vc + (db * 16 + s) * 72;
            us8 vf0 = *(const us8*)(vrow + g * 8);
            o_acc[db] = mfma16(pa[0], vf0, o_acc[db]);
            us8 vf1 = *(const us8*)(vrow + 32 + g * 8);
            o_acc[db] = mfma16(pa[1], vf1, o_acc[db]);
        }
        __builtin_amdgcn_s_setprio(0);
        cur ^= 1;
    }
    ATTN_EPILOGUE(qbB, o_acc, l_run);
}

// ---------------- output projection: O[4096][1024] x Wc[1024][1024]^T (both bf16) + bc ----------------
// 64x128 tiles, XCD-tiled: per XCD 8 bm x 8 bn (~1MB Ob + 2MB Wc in L2).
__global__ __launch_bounds__(256) void gemm_out(
    const unsigned short* __restrict__ O, const unsigned short* __restrict__ Wcb,
    const float* __restrict__ bc, float* __restrict__ out) {
    __shared__ unsigned short As[64 * 72];
    __shared__ unsigned short Bs[128 * 72];
    const int bid = blockIdx.x;
    const int xcd = bid & 7, idx = bid >> 3;     // idx 0..63
    const int bm = xcd * 8 + (idx & 7);          // 0..63
    const int bn = idx >> 3;                     // 0..7
    const int m0 = bm * 64, n0 = bn * 128;
    f32x4 acc[2][4];
    gemm_core_bb<2>(O, Wcb, 1024, m0, n0, As, Bs, acc);
    const int lane = threadIdx.x & 63, wid = threadIdx.x >> 6;
    const int g = lane >> 4, s = lane & 15, wr = wid >> 1, wc = wid & 1;
#pragma unroll
    for (int mi = 0; mi < 2; mi++)
#pragma unroll
        for (int ni = 0; ni < 4; ni++) {
            int ng = n0 + wc * 64 + ni * 16 + s;
            float bias = bc[ng];
#pragma unroll
            for (int r = 0; r < 4; r++) {
                int mg = m0 + wr * 32 + mi * 16 + 4 * g + r;
                out[(size_t)mg * 1024 + ng] = acc[mi][ni][r] + bias;
            }
        }
}

extern "C" void kernel_launch(void* const* d_in, const int* in_sizes, int n_in,
                              void* d_out, int out_size, void* d_ws, size_t ws_size,
                              hipStream_t stream) {
    const float* x  = (const float*)d_in[0];
    const float* Wq = (const float*)d_in[1];
    const float* Wk = (const float*)d_in[2];
    const float* Wv = (const float*)d_in[3];
    const float* Wc = (const float*)d_in[4];
    const float* bc = (const float*)d_in[5];
    float* out = (float*)d_out;

    if (ws_size < 33554432) {
        fill_sentinel<<<(out_size + 255) / 256, 256, 0, stream>>>(out, out_size);
        return;
    }
    char* w = (char*)d_ws;
    unsigned short* Qb  = (unsigned short*)(w);
    unsigned short* Kb  = (unsigned short*)(w + 8388608);
    unsigned short* VtG = (unsigned short*)(w + 16777216);   // [bh][d][t]
    unsigned short* Ob  = (unsigned short*)(w + 25165824);
    unsigned short* Wcb = (unsigned short*)(w);              // reuses Qb region after attn
    // d_out scratch: xb [0,8MB), wqkvb [8,14MB) -- dead before gemm_out writes out.
    unsigned short* xb    = (unsigned short*)d_out;
    unsigned short* wqkvb = (unsigned short*)((char*)d_out + 8388608);

    cvt_xw<<<7168, 256, 0, stream>>>(x, Wq, Wk, Wv, xb, wqkvb);
    gemm_qkv<<<768, 256, 0, stream>>>(xb, wqkvb, Qb, Kb, VtG);
    attn<<<512, 256, 0, stream>>>(Qb, Kb, VtG, Ob);
    cvt_wc<<<1024, 256, 0, stream>>>(Wc, Wcb);
    gemm_out<<<512, 256, 0, stream>>>(Ob, Wcb, bc, out);
}